// Round 8
// baseline (686.668 us; speedup 1.0000x reference)
//
#include <hip/hip_runtime.h>

// NATTEN 3D neighborhood attention — fp16 MFMA flash-style.
// B=1, T=16, H=32, W=32, nh=8, D=128, window (3,7,7), fp32 in/out.
//
// R10 = R9 + occupancy push to 4 blocks/CU.
//  - R9 post-mortem: fences were no-ops (dur/counters identical to R8).
//    VGPR_Count=84 (not at 168 cap) => no scratch spill; compiler uses
//    AGPRs for overflow. Unified total in (128,168] => 3 blocks/CU.
//  - LDS 39936 <= 40960 already permits 4 blocks/CU; only regs block it.
//  - launch_bounds(256,4): cap unified regs at 128.
//  - V prefetch split to shrink plateau: group A = keys 0..62 (2 its,
//    32 regs) issued pre-GEMM1; group B = keys 64..94 (1 it, 16 regs,
//    only 48 active threads) issued after barrier C, latency hidden
//    under group A's LDS writes.
//  - R8 core: XCD swizzle (head/XCD), setprio on MFMA, swapped GEMM1
//    (mfma(K,Q) -> lane&15=query, wave-private softmax), Q in VGPRs,
//    K(c+1) register prefetch riding across raw s_barriers.
// Structure: 64 queries/block (2,4,8), 8 chunks of (1,5,14)=70 keys
// (padded to 80/96), online softmax, GEMM2 O += P*V.

typedef _Float16 f16;
typedef _Float16 half8 __attribute__((ext_vector_type(8)));
typedef _Float16 half4 __attribute__((ext_vector_type(4)));
typedef _Float16 half2 __attribute__((ext_vector_type(2)));
typedef float floatx4 __attribute__((ext_vector_type(4)));
typedef float floatv4 __attribute__((ext_vector_type(4)));

#define CFENCE() asm volatile("" ::: "memory")
#define BAR_PLAIN() do { CFENCE(); __builtin_amdgcn_s_barrier(); CFENCE(); } while (0)
#define BAR_LDSW() do { asm volatile("s_waitcnt lgkmcnt(0)" ::: "memory"); \
                        __builtin_amdgcn_s_barrier(); CFENCE(); } while (0)
#define LIVE_FENCE() do { CFENCE(); __builtin_amdgcn_sched_barrier(0); } while (0)

namespace {

constexpr int T = 16, H = 32, W = 32, NH = 8, D = 128;
constexpr int QT = 2, QH = 4, QW = 8;  // 64 queries/block
constexpr float SCALE = 0.088388347648318447f;  // 128^-0.5

// padded frag-slot index (units of 16B slots): tile stride 69, qd stride 17
__device__ __forceinline__ int SLOT(int tile, int lr) {
  return tile * 69 + (lr >> 4) * 17 + (lr & 15);
}

__device__ __forceinline__ size_t goff(int tt, int hh, int ww, int head) {
  return ((size_t)((tt * H + hh) * W + ww) * NH + head) * D;
}

// exact floor(x/14) for 0 <= x < 96
__device__ __forceinline__ int div14(int x) { return (x * 586) >> 13; }

__global__ __launch_bounds__(256, 4) void na3d_mfma(
    const float* __restrict__ qp, const float* __restrict__ kp,
    const float* __restrict__ vp, float* __restrict__ op) {
  __shared__ alignas(16) f16 kvbuf[24 * 69 * 8];  // K/V frags 26496 B
  __shared__ alignas(16) f16 pbuf[12 * 69 * 8];   // P A-frags  13248 B

  // T1: XCD-aware swizzle. HW round-robins blockIdx%8 across XCDs; remap
  // so each XCD gets a contiguous logical range = one head (256 blocks).
  int bid = (int)(((blockIdx.x & 7) << 8) | (blockIdx.x >> 3));
  const int wb = bid & 3;  bid >>= 2;   // W/QW = 4
  const int hb = bid & 7;  bid >>= 3;   // H/QH = 8
  const int tb = bid & 7;  bid >>= 3;   // T/QT = 8
  const int head = bid;                 // 8

  const int t0 = tb * QT;
  const int h0 = hb * QH, w0 = wb * QW;
  const int bT = min(max(t0 - 1, 0), T - 4);    // key block T start (span 4)
  const int bH = min(max(h0 - 3, 0), H - 10);
  const int bW = min(max(w0 - 3, 0), W - 14);

  const int tid = threadIdx.x;
  const int wave = tid >> 6, lane = tid & 63;
  const int quad = lane >> 4, ln = lane & 15;
  const int kbase = quad * 4;

  // per-lane query (wave w owns queries w*16 .. w*16+15; lane's q^ = ln)
  const int toff = wave >> 1;
  const int hoff = (wave & 1) * 2 + (ln >> 3);
  const int woff = ln & 7;
  const int aT = min(max(t0 + toff - 1, 0), T - 3) - bT;   // 0..2
  const int aH = min(max(h0 + hoff - 3, 0), H - 7) - bH;   // 0..3
  const int aW = min(max(w0 + woff - 3, 0), W - 7) - bW;   // 0..7

  // ---- Q fragments in registers (B-operand: row n = ln = query) ----
  half8 qreg[4];
  {
    const size_t row = goff(t0 + toff, h0 + hoff, w0 + woff, head);
#pragma unroll
    for (int ks = 0; ks < 4; ++ks) {
      const int d0 = ks * 32 + quad * 8;
      const floatv4 x0 = *(const floatv4*)(qp + row + d0);
      const floatv4 x1 = *(const floatv4*)(qp + row + d0 + 4);
      half8 hv;
      hv[0] = (f16)(x0[0] * SCALE); hv[1] = (f16)(x0[1] * SCALE);
      hv[2] = (f16)(x0[2] * SCALE); hv[3] = (f16)(x0[3] * SCALE);
      hv[4] = (f16)(x1[0] * SCALE); hv[5] = (f16)(x1[1] * SCALE);
      hv[6] = (f16)(x1[2] * SCALE); hv[7] = (f16)(x1[3] * SCALE);
      qreg[ks] = hv;
    }
  }

  // zero never-written pbuf region (keys 80..95: tile wave*3+2, groups 2,3)
  if (quad >= 2) {
    *(floatx4*)&pbuf[SLOT(wave * 3 + 2, lane) * 8] = (floatx4){0.f, 0.f, 0.f, 0.f};
  }

  floatx4 oacc[8] = {{0.f, 0.f, 0.f, 0.f}, {0.f, 0.f, 0.f, 0.f},
                     {0.f, 0.f, 0.f, 0.f}, {0.f, 0.f, 0.f, 0.f},
                     {0.f, 0.f, 0.f, 0.f}, {0.f, 0.f, 0.f, 0.f},
                     {0.f, 0.f, 0.f, 0.f}, {0.f, 0.f, 0.f, 0.f}};
  float m_run = -1e30f, l_run = 0.f;  // per lane, for query q^ = ln

  floatv4 kreg[5][2];   // K prefetch (chunk c+1)
  floatv4 vregA[2][4];  // V prefetch group A: keys 0..62
  floatv4 vregB[4];     // V prefetch group B: keys 64..94 (48 threads)

  // ---- K prefetch for chunk 0 ----
  {
    const int tt = bT, kh0 = bH;
#pragma unroll
    for (int it = 0; it < 5; ++it) {
      const int s = tid + it * 256;
      if (s < 1120) {
        const int kk = s >> 4, dg = s & 15;
        const int khl = div14(kk), kw = kk - khl * 14;
        const size_t off = goff(tt, kh0 + khl, bW + kw, head) + dg * 8;
        kreg[it][0] = *(const floatv4*)(kp + off);
        kreg[it][1] = *(const floatv4*)(kp + off + 4);
      }
    }
  }

  for (int c = 0; c < 8; ++c) {
    const int dt = c >> 1;
    const int tt = bT + dt;
    const int kh0 = bH + (c & 1) * 5;
    const int hh5 = (c & 1) * 5;
    const bool tOK = (dt >= aT) && (dt < aT + 3);

    // ---- barrier A: all waves done with kvbuf V reads (GEMM2 of c-1) ----
    BAR_PLAIN();

    // ---- K LDS write from kreg (frag-order b128); kreg DIES here ----
#pragma unroll
    for (int it = 0; it < 5; ++it) {
      const int s = tid + it * 256;
      if (s < 1120) {
        const int kk = s >> 4, dg = s & 15;
        const floatv4 a0 = kreg[it][0], a1 = kreg[it][1];
        half8 hv;
        hv[0] = (f16)a0[0]; hv[1] = (f16)a0[1];
        hv[2] = (f16)a0[2]; hv[3] = (f16)a0[3];
        hv[4] = (f16)a1[0]; hv[5] = (f16)a1[1];
        hv[6] = (f16)a1[2]; hv[7] = (f16)a1[3];
        *(half8*)&kvbuf[SLOT((kk >> 4) * 4 + (dg >> 2),
                             (dg & 3) * 16 + (kk & 15)) * 8] = hv;
      }
    }
    LIVE_FENCE();

    // ---- issue V group A (keys 0..62; consumed after barrier C) ----
#pragma unroll
    for (int it = 0; it < 2; ++it) {
      const int s = tid + it * 256;
      const int p = s >> 4, dg = s & 15;
      const int kk0 = p * 2;  // 0..62, always valid
      const int khl = div14(kk0), kw = kk0 - khl * 14;
      const size_t off = goff(tt, kh0 + khl, bW + kw, head) + dg * 8;
      vregA[it][0] = *(const floatv4*)(vp + off);
      vregA[it][1] = *(const floatv4*)(vp + off + 4);
      vregA[it][2] = *(const floatv4*)(vp + off + 1024);   // key kk0+1
      vregA[it][3] = *(const floatv4*)(vp + off + 1028);
    }

    // ---- barrier B: K visible (wait own LDS writes, not vmcnt) ----
    BAR_LDSW();

    // ---- GEMM1 (swapped): acc1[kt] = S^T[key][query] ----
    floatx4 acc1[5] = {{0.f, 0.f, 0.f, 0.f}, {0.f, 0.f, 0.f, 0.f},
                       {0.f, 0.f, 0.f, 0.f}, {0.f, 0.f, 0.f, 0.f},
                       {0.f, 0.f, 0.f, 0.f}};
    __builtin_amdgcn_s_setprio(1);
#pragma unroll
    for (int kt = 0; kt < 5; ++kt) {
#pragma unroll
      for (int ks = 0; ks < 4; ++ks) {
        const half8 a = *(const half8*)&kvbuf[SLOT(kt * 4 + ks, lane) * 8];
        acc1[kt] =
            __builtin_amdgcn_mfma_f32_16x16x32_f16(a, qreg[ks], acc1[kt], 0, 0, 0);
      }
    }
    __builtin_amdgcn_s_setprio(0);

    // ---- barrier C: all waves done reading K from kvbuf ----
    BAR_PLAIN();

    // ---- issue V group B (keys 64..94; only tid<48 load, rest zero) ----
    {
      const int s = tid + 512;
      const int p = s >> 4, dg = s & 15;
      const int kk0 = p * 2;  // 64..94
      if (kk0 < 70) {
        const int khl = div14(kk0), kw = kk0 - khl * 14;
        const size_t off = goff(tt, kh0 + khl, bW + kw, head) + dg * 8;
        vregB[0] = *(const floatv4*)(vp + off);
        vregB[1] = *(const floatv4*)(vp + off + 4);
        vregB[2] = *(const floatv4*)(vp + off + 1024);
        vregB[3] = *(const floatv4*)(vp + off + 1028);
      } else {
        vregB[0] = (floatv4){0.f, 0.f, 0.f, 0.f};
        vregB[1] = (floatv4){0.f, 0.f, 0.f, 0.f};
        vregB[2] = (floatv4){0.f, 0.f, 0.f, 0.f};
        vregB[3] = (floatv4){0.f, 0.f, 0.f, 0.f};
      }
    }

    // ---- V LDS write group A (key-pair packed b32); vregA DIES here ----
#pragma unroll
    for (int it = 0; it < 2; ++it) {
      const int s = tid + it * 256;
      const int p = s >> 4, dg = s & 15;
      const int kk0 = p * 2;
      const int kst = kk0 >> 5, qd = (kk0 >> 3) & 3, j0 = kk0 & 7;
      const int tbase = (dg >> 1) * 3 + kst;
      const int lrb = qd * 16 + (dg & 1) * 8;
#pragma unroll
      for (int u = 0; u < 8; ++u) {
        half2 h;
        h[0] = (f16)vregA[it][u >> 2][u & 3];
        h[1] = (f16)vregA[it][2 + (u >> 2)][u & 3];
        *(half2*)&kvbuf[SLOT(tbase, lrb + u) * 8 + j0] = h;
      }
    }
    // ---- V LDS write group B; vregB DIES here ----
    {
      const int s = tid + 512;
      const int p = s >> 4, dg = s & 15;
      const int kk0 = p * 2;
      const int kst = kk0 >> 5, qd = (kk0 >> 3) & 3, j0 = kk0 & 7;
      const int tbase = (dg >> 1) * 3 + kst;
      const int lrb = qd * 16 + (dg & 1) * 8;
#pragma unroll
      for (int u = 0; u < 8; ++u) {
        half2 h;
        h[0] = (f16)vregB[u >> 2][u & 3];
        h[1] = (f16)vregB[2 + (u >> 2)][u & 3];
        *(half2*)&kvbuf[SLOT(tbase, lrb + u) * 8 + j0] = h;
      }
    }
    LIVE_FENCE();

    // ---- issue K global loads for chunk c+1 ----
    if (c < 7) {
      const int cc = c + 1;
      const int ttn = bT + (cc >> 1);
      const int kh0n = bH + (cc & 1) * 5;
#pragma unroll
      for (int it = 0; it < 5; ++it) {
        const int s = tid + it * 256;
        if (s < 1120) {
          const int kk = s >> 4, dg = s & 15;
          const int khl = div14(kk), kw = kk - khl * 14;
          const size_t off = goff(ttn, kh0n + khl, bW + kw, head) + dg * 8;
          kreg[it][0] = *(const floatv4*)(kp + off);
          kreg[it][1] = *(const floatv4*)(kp + off + 4);
        }
      }
    }

    // ---- wave-private softmax (register-local; q^ = ln per lane) ----
    float pm = -1e30f;
#pragma unroll
    for (int kt = 0; kt < 5; ++kt) {
#pragma unroll
      for (int r = 0; r < 4; ++r) {
        const int kk = kt * 16 + kbase + r;
        const int khl = div14(kk), kw = kk - khl * 14;
        const int kha = hh5 + khl;
        const bool ok = tOK && (kk < 70) && ((unsigned)(kha - aH) < 7u) &&
                        ((unsigned)(kw - aW) < 7u);
        const float sv = ok ? acc1[kt][r] : -INFINITY;
        acc1[kt][r] = sv;
        pm = fmaxf(pm, sv);
      }
    }
    pm = fmaxf(pm, __shfl_xor(pm, 16));
    pm = fmaxf(pm, __shfl_xor(pm, 32));
    const float mN = fmaxf(m_run, pm);
    const float alpha = __expf(m_run - mN);
    m_run = mN;

    float ps = 0.f;
#pragma unroll
    for (int kt = 0; kt < 5; ++kt) {
      half4 h;
#pragma unroll
      for (int r = 0; r < 4; ++r) {
        const float e = __expf(acc1[kt][r] - mN);  // -inf -> 0
        ps += e;
        h[r] = (f16)e;
      }
      *(half4*)&pbuf[SLOT(wave * 3 + (kt >> 1),
                          ((kt & 1) * 2 + (quad >> 1)) * 16 + ln) * 8 +
                     (quad & 1) * 4] = h;
    }
    ps += __shfl_xor(ps, 16);
    ps += __shfl_xor(ps, 32);
    l_run = l_run * alpha + ps;

    // ---- barrier D: V + P visible ----
    BAR_LDSW();
    __builtin_amdgcn_sched_barrier(0);

    // ---- GEMM2: O = alpha*O + P*V ----
    floatx4 af;
#pragma unroll
    for (int r = 0; r < 4; ++r) af[r] = __shfl(alpha, kbase + r);
#pragma unroll
    for (int u = 0; u < 8; ++u) oacc[u] *= af;
    __builtin_amdgcn_s_setprio(1);
#pragma unroll
    for (int ks = 0; ks < 3; ++ks) {
      const half8 a = *(const half8*)&pbuf[SLOT(wave * 3 + ks, lane) * 8];
#pragma unroll
      for (int u = 0; u < 8; ++u) {
        const half8 b = *(const half8*)&kvbuf[SLOT(u * 3 + ks, lane) * 8];
        oacc[u] = __builtin_amdgcn_mfma_f32_16x16x32_f16(a, b, oacc[u], 0, 0, 0);
      }
    }
    __builtin_amdgcn_s_setprio(0);
  }

  // ---- epilogue: O / l, write out ----
  const float linv = 1.f / l_run;
  floatx4 lf;
#pragma unroll
  for (int r = 0; r < 4; ++r) lf[r] = __shfl(linv, kbase + r);
#pragma unroll
  for (int r = 0; r < 4; ++r) {
    const int q = wave * 16 + quad * 4 + r;
    const size_t off =
        goff(t0 + (q >> 5), h0 + ((q >> 3) & 3), w0 + (q & 7), head);
#pragma unroll
    for (int u = 0; u < 8; ++u)
      op[off + u * 16 + ln] = oacc[u][r] * lf[r];
  }
}

}  // namespace

extern "C" void kernel_launch(void* const* d_in, const int* in_sizes, int n_in,
                              void* d_out, int out_size, void* d_ws,
                              size_t ws_size, hipStream_t stream) {
  const float* q = (const float*)d_in[0];
  const float* k = (const float*)d_in[1];
  const float* v = (const float*)d_in[2];
  float* out = (float*)d_out;
  const int nblocks = NH * (T / QT) * (H / QH) * (W / QW);  // 2048
  na3d_mfma<<<dim3(nblocks), dim3(256), 0, stream>>>(q, k, v, out);
}